// Round 1
// baseline (8374.540 us; speedup 1.0000x reference)
//
#include <hip/hip_runtime.h>
#include <math.h>

#define N_ENTS 50000
#define N_RELS 500
#define N_ALL  50500
#define EMB    256
#define NEDGE  400000
#define BATCH  512
#define BN_EPS 1e-5f

// ---------------------------------------------------------------------------
// Build hamilton matrix H (4P x 256) from W (P x 256), quaternion structure.
// H[a*P+p][c*64+s] = sgn[a][c] * W[p][comp[a][c]*64 + s]
// ---------------------------------------------------------------------------
__global__ __launch_bounds__(256) void build_hamilton_kernel(
    const float* __restrict__ W, float* __restrict__ H, int P) {
    int idx = blockIdx.x * 256 + threadIdx.x;
    int total = 4 * P * 256;
    if (idx >= total) return;
    int row = idx >> 8;
    int cc  = idx & 255;
    int a = row / P, p = row % P;
    int c = cc >> 6, s = cc & 63;
    const int  comp[4][4] = {{0,1,2,3},{1,0,3,2},{2,3,0,1},{3,2,1,0}};
    const float sgn[4][4] = {{1.f,1.f,1.f,1.f},
                             {-1.f,1.f,1.f,-1.f},
                             {-1.f,-1.f,1.f,1.f},
                             {-1.f,1.f,-1.f,1.f}};
    H[idx] = sgn[a][c] * W[p * 256 + comp[a][c] * 64 + s];
}

// ---------------------------------------------------------------------------
// Generic f32 NN GEMM: C[M,N] = A[M,K] @ B[K,N].  N multiple of 64 (N=256).
// 64x64 tile, BK=16, 256 threads, 4x4 microtile.
// ---------------------------------------------------------------------------
__global__ __launch_bounds__(256) void gemm_nn_kernel(
    const float* __restrict__ A, const float* __restrict__ B,
    float* __restrict__ C, int M, int K, int N) {
    __shared__ float As[16][65];
    __shared__ float Bs[16][65];
    int tid = threadIdx.x;
    int tx = tid & 15, ty = tid >> 4;
    int bm0 = blockIdx.y * 64;
    int bn0 = blockIdx.x * 64;
    float acc[4][4] = {};
    for (int k0 = 0; k0 < K; k0 += 16) {
#pragma unroll
        for (int i = 0; i < 4; i++) {
            int e = tid + i * 256;
            int m = e >> 4, k = e & 15;
            int gm = bm0 + m;
            As[k][m] = (gm < M) ? A[(long)gm * K + k0 + k] : 0.f;
            int n = e & 63, kb = e >> 6;
            Bs[kb][n] = B[(long)(k0 + kb) * N + bn0 + n];
        }
        __syncthreads();
#pragma unroll
        for (int k = 0; k < 16; k++) {
            float av[4], bv[4];
#pragma unroll
            for (int i = 0; i < 4; i++) av[i] = As[k][ty * 4 + i];
#pragma unroll
            for (int j = 0; j < 4; j++) bv[j] = Bs[k][tx * 4 + j];
#pragma unroll
            for (int i = 0; i < 4; i++)
#pragma unroll
                for (int j = 0; j < 4; j++)
                    acc[i][j] = fmaf(av[i], bv[j], acc[i][j]);
        }
        __syncthreads();
    }
#pragma unroll
    for (int i = 0; i < 4; i++) {
        int gm = bm0 + ty * 4 + i;
        if (gm < M) {
#pragma unroll
            for (int j = 0; j < 4; j++)
                C[(long)gm * N + bn0 + tx * 4 + j] = acc[i][j];
        }
    }
}

// ---------------------------------------------------------------------------
// Lin GEMM: C[50000,256] = Xcat[50000,512] @ B[512,256], where Xcat columns
// interleave Xef/Xrf quarters: chunk = kk>>6, even->Xef, odd->Xrf,
// source col = (chunk>>1)*64 + (kk&63).
// ---------------------------------------------------------------------------
__global__ __launch_bounds__(256) void gemm_lin_kernel(
    const float* __restrict__ Xef, const float* __restrict__ Xrf,
    const float* __restrict__ B, float* __restrict__ C, int M) {
    const int K = 512, N = 256;
    __shared__ float As[16][65];
    __shared__ float Bs[16][65];
    int tid = threadIdx.x;
    int tx = tid & 15, ty = tid >> 4;
    int bm0 = blockIdx.y * 64;
    int bn0 = blockIdx.x * 64;
    float acc[4][4] = {};
    for (int k0 = 0; k0 < K; k0 += 16) {
#pragma unroll
        for (int i = 0; i < 4; i++) {
            int e = tid + i * 256;
            int m = e >> 4, k = e & 15;
            int gm = bm0 + m;
            int kk = k0 + k;
            int chunk = kk >> 6, s = kk & 63;
            const float* src = (chunk & 1) ? Xrf : Xef;
            As[k][m] = (gm < M) ? src[(long)gm * 256 + (chunk >> 1) * 64 + s] : 0.f;
            int n = e & 63, kb = e >> 6;
            Bs[kb][n] = B[(long)(k0 + kb) * N + bn0 + n];
        }
        __syncthreads();
#pragma unroll
        for (int k = 0; k < 16; k++) {
            float av[4], bv[4];
#pragma unroll
            for (int i = 0; i < 4; i++) av[i] = As[k][ty * 4 + i];
#pragma unroll
            for (int j = 0; j < 4; j++) bv[j] = Bs[k][tx * 4 + j];
#pragma unroll
            for (int i = 0; i < 4; i++)
#pragma unroll
                for (int j = 0; j < 4; j++)
                    acc[i][j] = fmaf(av[i], bv[j], acc[i][j]);
        }
        __syncthreads();
    }
#pragma unroll
    for (int i = 0; i < 4; i++) {
        int gm = bm0 + ty * 4 + i;
        if (gm < M) {
#pragma unroll
            for (int j = 0; j < 4; j++)
                C[(long)gm * N + bn0 + tx * 4 + j] = acc[i][j];
        }
    }
}

// ---------------------------------------------------------------------------
// Score GEMM (NT) + sigmoid: out[b,e] = sigmoid(dot(hrn[b,:], X[e,:]))
// M=512 batch, N=50000 ents, K=256.
// ---------------------------------------------------------------------------
__global__ __launch_bounds__(256) void gemm_nt_sig_kernel(
    const float* __restrict__ A,   // hrn (512,256)
    const float* __restrict__ Bt,  // X (50000,256)
    float* __restrict__ out) {
    __shared__ float As[16][65];
    __shared__ float Bs[16][65];
    int tid = threadIdx.x;
    int tx = tid & 15, ty = tid >> 4;
    int bm0 = blockIdx.y * 64;  // batch
    int bn0 = blockIdx.x * 64;  // ents
    float acc[4][4] = {};
    for (int k0 = 0; k0 < 256; k0 += 16) {
#pragma unroll
        for (int i = 0; i < 4; i++) {
            int e = tid + i * 256;
            int m = e >> 4, k = e & 15;
            As[k][m] = A[(long)(bm0 + m) * 256 + k0 + k];
            int gn = bn0 + m;
            Bs[k][m] = (gn < N_ENTS) ? Bt[(long)gn * 256 + k0 + k] : 0.f;
        }
        __syncthreads();
#pragma unroll
        for (int k = 0; k < 16; k++) {
            float av[4], bv[4];
#pragma unroll
            for (int i = 0; i < 4; i++) av[i] = As[k][ty * 4 + i];
#pragma unroll
            for (int j = 0; j < 4; j++) bv[j] = Bs[k][tx * 4 + j];
#pragma unroll
            for (int i = 0; i < 4; i++)
#pragma unroll
                for (int j = 0; j < 4; j++)
                    acc[i][j] = fmaf(av[i], bv[j], acc[i][j]);
        }
        __syncthreads();
    }
#pragma unroll
    for (int i = 0; i < 4; i++) {
        int b = bm0 + ty * 4 + i;
#pragma unroll
        for (int j = 0; j < 4; j++) {
            int e = bn0 + tx * 4 + j;
            if (e < N_ENTS) {
                float v = acc[i][j];
                out[(long)b * N_ENTS + e] = 1.f / (1.f + __expf(-v));
            }
        }
    }
}

// ---------------------------------------------------------------------------
// Segment sum: agg[rows[e], :] += vals[e] * support[cols[e], :]
// One 64-lane wave per edge; each lane handles 4 consecutive floats.
// ---------------------------------------------------------------------------
__global__ __launch_bounds__(256) void seg_sum_kernel(
    const float* __restrict__ support, const int* __restrict__ rows,
    const int* __restrict__ cols, const float* __restrict__ vals,
    float* __restrict__ agg, int n_edges) {
    int gid = blockIdx.x * 256 + threadIdx.x;
    int edge = gid >> 6;
    int lane = gid & 63;
    if (edge >= n_edges) return;
    int col = cols[edge];
    int row = rows[edge];
    float v = vals[edge];
    const float4 s = *(const float4*)(support + (long)col * 256 + lane * 4);
    float* dst = agg + (long)row * 256 + lane * 4;
    atomicAdd(dst + 0, v * s.x);
    atomicAdd(dst + 1, v * s.y);
    atomicAdd(dst + 2, v * s.z);
    atomicAdd(dst + 3, v * s.w);
}

// ---------------------------------------------------------------------------
// Column stats: stats[c] += sum, stats[256+c] += sumsq over a 256-row chunk.
// ---------------------------------------------------------------------------
__global__ __launch_bounds__(256) void bn_stats_kernel(
    const float* __restrict__ x, int n, float* __restrict__ stats) {
    int col = threadIdx.x;
    int r0 = blockIdx.x * 256;
    int r1 = r0 + 256;
    if (r1 > n) r1 = n;
    float s = 0.f, sq = 0.f;
    for (int r = r0; r < r1; r++) {
        float v = x[(long)r * 256 + col];
        s += v;
        sq += v * v;
    }
    atomicAdd(&stats[col], s);
    atomicAdd(&stats[256 + col], sq);
}

// ---------------------------------------------------------------------------
// BN apply (+ optional tanh):  y = gamma*(x-mean)*rsqrt(var+eps)+beta
// var is biased (divide by n), matching jnp.var.
// ---------------------------------------------------------------------------
template <bool TANH>
__global__ __launch_bounds__(256) void bn_apply_kernel(
    const float* __restrict__ x, float* __restrict__ y, int n,
    const float* __restrict__ gamma, const float* __restrict__ beta,
    const float* __restrict__ stats) {
    long total = (long)n * 256;
    float inv_n = 1.f / (float)n;
    for (long idx = (long)blockIdx.x * 256 + threadIdx.x; idx < total;
         idx += (long)gridDim.x * 256) {
        int col = (int)(idx & 255);
        float mean = stats[col] * inv_n;
        float var = stats[256 + col] * inv_n - mean * mean;
        float sc = rsqrtf(var + BN_EPS) * gamma[col];
        float v = (x[idx] - mean) * sc + beta[col];
        if (TANH) v = tanhf(v);
        y[idx] = v;
    }
}

// ---------------------------------------------------------------------------
// Quaternion vec-vec multiplication: hr (512,256) from h=X[e1], p=R[r].
// One thread per (b, s) with s in [0,64).
// ---------------------------------------------------------------------------
__global__ __launch_bounds__(256) void hr_kernel(
    const float* __restrict__ X, const float* __restrict__ R,
    const int* __restrict__ e1_idx, const int* __restrict__ r_idx,
    float* __restrict__ hr) {
    int idx = blockIdx.x * 256 + threadIdx.x;
    if (idx >= BATCH * 64) return;
    int b = idx >> 6, s = idx & 63;
    const float* h = X + (long)e1_idx[b] * 256;
    const float* p = R + (long)r_idx[b] * 256;
    float qr = h[s], qi = h[64 + s], qj = h[128 + s], qk = h[192 + s];
    float pr = p[s], pi = p[64 + s], pj = p[128 + s], pk = p[192 + s];
    float inv = rsqrtf(pr * pr + pi * pi + pj * pj + pk * pk);
    pr *= inv; pi *= inv; pj *= inv; pk *= inv;
    float* o = hr + (long)b * 256 + s;
    o[0]   = qr * pr - qi * pi - qj * pj - qk * pk;
    o[64]  = qi * pr + qr * pi - qk * pj + qj * pk;
    o[128] = qj * pr + qk * pi + qr * pj - qi * pk;
    o[192] = qk * pr - qj * pi + qi * pj + qr * pk;
}

// ---------------------------------------------------------------------------
// Host-side orchestration helpers
// ---------------------------------------------------------------------------
struct Ws {
    float* supportBuf;  // (50500,256)
    float* aggA;        // (50500,256)  -> XRrf in-place
    float* aggB;        // (50000,256)  -> Xef in-place
    float* XRcur;       // (50500,256)
    float* H256;        // (256,256)
    float* H512;        // (512,256)
    float* hr;          // (512,256)
    float* hrn;         // (512,256)
    float* stats;       // 512
};

static void run_bn(float* buf, float* outbuf, int n, const float* gamma,
                   const float* beta, bool do_tanh, const Ws& w,
                   hipStream_t stream) {
    hipMemsetAsync(w.stats, 0, 512 * sizeof(float), stream);
    bn_stats_kernel<<<(n + 255) / 256, 256, 0, stream>>>(buf, n, w.stats);
    long total = (long)n * 256;
    int blocks = (int)((total + 255) / 256);
    if (blocks > 2048) blocks = 2048;
    if (do_tanh)
        bn_apply_kernel<true><<<blocks, 256, 0, stream>>>(buf, outbuf, n, gamma, beta, w.stats);
    else
        bn_apply_kernel<false><<<blocks, 256, 0, stream>>>(buf, outbuf, n, gamma, beta, w.stats);
}

static void run_q4gnn(const float* Xin, int n, const int* rows, const int* cols,
                      const float* vals, const float* W, const float* gamma,
                      const float* beta, float* agg, const Ws& w,
                      hipStream_t stream) {
    build_hamilton_kernel<<<(4 * 64 * 256) / 256, 256, 0, stream>>>(W, w.H256, 64);
    dim3 g(4, (n + 63) / 64);
    gemm_nn_kernel<<<g, 256, 0, stream>>>(Xin, w.H256, w.supportBuf, n, 256, 256);
    hipMemsetAsync(agg, 0, (size_t)n * 256 * sizeof(float), stream);
    seg_sum_kernel<<<(NEDGE * 64) / 256, 256, 0, stream>>>(w.supportBuf, rows, cols, vals, agg, NEDGE);
    run_bn(agg, agg, n, gamma, beta, true, w, stream);
}

static void run_score(const float* X, const float* R, const int* e1_idx,
                      const int* r_idx, const float* gamma, const float* beta,
                      float* out_l, const Ws& w, hipStream_t stream) {
    hr_kernel<<<(BATCH * 64) / 256, 256, 0, stream>>>(X, R, e1_idx, r_idx, w.hr);
    run_bn(w.hr, w.hrn, BATCH, gamma, beta, false, w, stream);
    dim3 g((N_ENTS + 63) / 64, BATCH / 64);
    gemm_nt_sig_kernel<<<g, 256, 0, stream>>>(w.hrn, X, out_l);
}

extern "C" void kernel_launch(void* const* d_in, const int* in_sizes, int n_in,
                              void* d_out, int out_size, void* d_ws, size_t ws_size,
                              hipStream_t stream) {
    const int*   e1_idx     = (const int*)d_in[0];
    const int*   r_idx      = (const int*)d_in[1];
    const float* emb        = (const float*)d_in[2];
    const float* gcn1_w     = (const float*)d_in[3];
    const float* gcn2_w     = (const float*)d_in[4];
    const float* gcn1_gamma = (const float*)d_in[5];
    const float* gcn1_beta  = (const float*)d_in[6];
    const float* gcn2_gamma = (const float*)d_in[7];
    const float* gcn2_beta  = (const float*)d_in[8];
    const float* lin_ents   = (const float*)d_in[9];
    const float* bn_s_gamma = (const float*)d_in[10];
    const float* bn_s_beta  = (const float*)d_in[11];
    const int*   adj_rows   = (const int*)d_in[12];
    const int*   adj_cols   = (const int*)d_in[13];
    const float* adj_vals   = (const float*)d_in[14];
    const int*   adjr_rows  = (const int*)d_in[15];
    const int*   adjr_cols  = (const int*)d_in[16];
    const float* adjr_vals  = (const float*)d_in[17];
    float* out = (float*)d_out;

    Ws w;
    float* f = (float*)d_ws;
    w.supportBuf = f; f += (long)N_ALL * EMB;
    w.aggA       = f; f += (long)N_ALL * EMB;
    w.aggB       = f; f += (long)N_ENTS * EMB;
    w.XRcur      = f; f += (long)N_ALL * EMB;
    w.H256       = f; f += 256 * 256;
    w.H512       = f; f += 512 * 256;
    w.hr         = f; f += BATCH * EMB;
    w.hrn        = f; f += BATCH * EMB;
    w.stats      = f; f += 512;

    // score 0: X = emb[:50000], R = emb[50000:]
    run_score(emb, emb + (long)N_ENTS * EMB, e1_idx, r_idx,
              bn_s_gamma, bn_s_beta, out, w, stream);

    for (int l = 0; l < 2; l++) {
        const float* XRptr = (l == 0) ? emb : w.XRcur;
        // XRrf (into aggA, in-place bn+tanh)
        run_q4gnn(XRptr, N_ALL, adjr_rows, adjr_cols, adjr_vals,
                  gcn2_w + (long)l * 64 * 256, gcn2_gamma + l * 256,
                  gcn2_beta + l * 256, w.aggA, w, stream);
        // Xef (into aggB)
        run_q4gnn(XRptr, N_ENTS, adj_rows, adj_cols, adj_vals,
                  gcn1_w + (long)l * 64 * 256, gcn1_gamma + l * 256,
                  gcn1_beta + l * 256, w.aggB, w, stream);
        // X_next = Xcat @ quat(lin_ents[l])   (Xcat folded into loader)
        build_hamilton_kernel<<<(4 * 128 * 256) / 256, 256, 0, stream>>>(
            lin_ents + (long)l * 128 * 256, w.H512, 128);
        dim3 g(4, (N_ENTS + 63) / 64);
        gemm_lin_kernel<<<g, 256, 0, stream>>>(w.aggB, w.aggA, w.H512, w.XRcur, N_ENTS);
        // R_next = XRrf[50000:]
        hipMemcpyAsync(w.XRcur + (long)N_ENTS * EMB, w.aggA + (long)N_ENTS * EMB,
                       (size_t)N_RELS * EMB * sizeof(float),
                       hipMemcpyDeviceToDevice, stream);
        // score l+1
        run_score(w.XRcur, w.XRcur + (long)N_ENTS * EMB, e1_idx, r_idx,
                  bn_s_gamma + (l + 1) * 256, bn_s_beta + (l + 1) * 256,
                  out + (long)(l + 1) * BATCH * N_ENTS, w, stream);
    }
}

// Round 2
// 3422.538 us; speedup vs baseline: 2.4469x; 2.4469x over previous
//
#include <hip/hip_runtime.h>
#include <math.h>

#define N_ENTS 50000
#define N_RELS 500
#define N_ALL  50500
#define EMB    256
#define NEDGE  400000
#define BATCH  512
#define BN_EPS 1e-5f

// ---------------------------------------------------------------------------
// Build hamilton matrix H (4P x 256) from W (P x 256), quaternion structure.
// ---------------------------------------------------------------------------
__global__ __launch_bounds__(256) void build_hamilton_kernel(
    const float* __restrict__ W, float* __restrict__ H, int P) {
    int idx = blockIdx.x * 256 + threadIdx.x;
    int total = 4 * P * 256;
    if (idx >= total) return;
    int row = idx >> 8;
    int cc  = idx & 255;
    int a = row / P, p = row % P;
    int c = cc >> 6, s = cc & 63;
    const int  comp[4][4] = {{0,1,2,3},{1,0,3,2},{2,3,0,1},{3,2,1,0}};
    const float sgn[4][4] = {{1.f,1.f,1.f,1.f},
                             {-1.f,1.f,1.f,-1.f},
                             {-1.f,-1.f,1.f,1.f},
                             {-1.f,1.f,-1.f,1.f}};
    H[idx] = sgn[a][c] * W[p * 256 + comp[a][c] * 64 + s];
}

// ---------------------------------------------------------------------------
// Generic f32 NN GEMM: C[M,N] = A[M,K] @ B[K,N].  64x64 tile, BK=16.
// ---------------------------------------------------------------------------
__global__ __launch_bounds__(256) void gemm_nn_kernel(
    const float* __restrict__ A, const float* __restrict__ B,
    float* __restrict__ C, int M, int K, int N) {
    __shared__ float As[16][65];
    __shared__ float Bs[16][65];
    int tid = threadIdx.x;
    int tx = tid & 15, ty = tid >> 4;
    int bm0 = blockIdx.y * 64;
    int bn0 = blockIdx.x * 64;
    float acc[4][4] = {};
    for (int k0 = 0; k0 < K; k0 += 16) {
#pragma unroll
        for (int i = 0; i < 4; i++) {
            int e = tid + i * 256;
            int m = e >> 4, k = e & 15;
            int gm = bm0 + m;
            As[k][m] = (gm < M) ? A[(long)gm * K + k0 + k] : 0.f;
            int n = e & 63, kb = e >> 6;
            Bs[kb][n] = B[(long)(k0 + kb) * N + bn0 + n];
        }
        __syncthreads();
#pragma unroll
        for (int k = 0; k < 16; k++) {
            float av[4], bv[4];
#pragma unroll
            for (int i = 0; i < 4; i++) av[i] = As[k][ty * 4 + i];
#pragma unroll
            for (int j = 0; j < 4; j++) bv[j] = Bs[k][tx * 4 + j];
#pragma unroll
            for (int i = 0; i < 4; i++)
#pragma unroll
                for (int j = 0; j < 4; j++)
                    acc[i][j] = fmaf(av[i], bv[j], acc[i][j]);
        }
        __syncthreads();
    }
#pragma unroll
    for (int i = 0; i < 4; i++) {
        int gm = bm0 + ty * 4 + i;
        if (gm < M) {
#pragma unroll
            for (int j = 0; j < 4; j++)
                C[(long)gm * N + bn0 + tx * 4 + j] = acc[i][j];
        }
    }
}

// ---------------------------------------------------------------------------
// Lin GEMM: C[50000,256] = Xcat[50000,512] @ B[512,256]; Xcat column
// interleave folded into the A loader.
// ---------------------------------------------------------------------------
__global__ __launch_bounds__(256) void gemm_lin_kernel(
    const float* __restrict__ Xef, const float* __restrict__ Xrf,
    const float* __restrict__ B, float* __restrict__ C, int M) {
    const int K = 512, N = 256;
    __shared__ float As[16][65];
    __shared__ float Bs[16][65];
    int tid = threadIdx.x;
    int tx = tid & 15, ty = tid >> 4;
    int bm0 = blockIdx.y * 64;
    int bn0 = blockIdx.x * 64;
    float acc[4][4] = {};
    for (int k0 = 0; k0 < K; k0 += 16) {
#pragma unroll
        for (int i = 0; i < 4; i++) {
            int e = tid + i * 256;
            int m = e >> 4, k = e & 15;
            int gm = bm0 + m;
            int kk = k0 + k;
            int chunk = kk >> 6, s = kk & 63;
            const float* src = (chunk & 1) ? Xrf : Xef;
            As[k][m] = (gm < M) ? src[(long)gm * 256 + (chunk >> 1) * 64 + s] : 0.f;
            int n = e & 63, kb = e >> 6;
            Bs[kb][n] = B[(long)(k0 + kb) * N + bn0 + n];
        }
        __syncthreads();
#pragma unroll
        for (int k = 0; k < 16; k++) {
            float av[4], bv[4];
#pragma unroll
            for (int i = 0; i < 4; i++) av[i] = As[k][ty * 4 + i];
#pragma unroll
            for (int j = 0; j < 4; j++) bv[j] = Bs[k][tx * 4 + j];
#pragma unroll
            for (int i = 0; i < 4; i++)
#pragma unroll
                for (int j = 0; j < 4; j++)
                    acc[i][j] = fmaf(av[i], bv[j], acc[i][j]);
        }
        __syncthreads();
    }
#pragma unroll
    for (int i = 0; i < 4; i++) {
        int gm = bm0 + ty * 4 + i;
        if (gm < M) {
#pragma unroll
            for (int j = 0; j < 4; j++)
                C[(long)gm * N + bn0 + tx * 4 + j] = acc[i][j];
        }
    }
}

// ---------------------------------------------------------------------------
// Score GEMM (NT) + sigmoid: out[b,e] = sigmoid(dot(hrn[b,:], X[e,:]))
// ---------------------------------------------------------------------------
__global__ __launch_bounds__(256) void gemm_nt_sig_kernel(
    const float* __restrict__ A,   // hrn (512,256)
    const float* __restrict__ Bt,  // X (50000,256)
    float* __restrict__ out) {
    __shared__ float As[16][65];
    __shared__ float Bs[16][65];
    int tid = threadIdx.x;
    int tx = tid & 15, ty = tid >> 4;
    int bm0 = blockIdx.y * 64;  // batch
    int bn0 = blockIdx.x * 64;  // ents
    float acc[4][4] = {};
    for (int k0 = 0; k0 < 256; k0 += 16) {
#pragma unroll
        for (int i = 0; i < 4; i++) {
            int e = tid + i * 256;
            int m = e >> 4, k = e & 15;
            As[k][m] = A[(long)(bm0 + m) * 256 + k0 + k];
            int gn = bn0 + m;
            Bs[k][m] = (gn < N_ENTS) ? Bt[(long)gn * 256 + k0 + k] : 0.f;
        }
        __syncthreads();
#pragma unroll
        for (int k = 0; k < 16; k++) {
            float av[4], bv[4];
#pragma unroll
            for (int i = 0; i < 4; i++) av[i] = As[k][ty * 4 + i];
#pragma unroll
            for (int j = 0; j < 4; j++) bv[j] = Bs[k][tx * 4 + j];
#pragma unroll
            for (int i = 0; i < 4; i++)
#pragma unroll
                for (int j = 0; j < 4; j++)
                    acc[i][j] = fmaf(av[i], bv[j], acc[i][j]);
        }
        __syncthreads();
    }
#pragma unroll
    for (int i = 0; i < 4; i++) {
        int b = bm0 + ty * 4 + i;
#pragma unroll
        for (int j = 0; j < 4; j++) {
            int e = bn0 + tx * 4 + j;
            if (e < N_ENTS) {
                float v = acc[i][j];
                out[(long)b * N_ENTS + e] = 1.f / (1.f + __expf(-v));
            }
        }
    }
}

// ---------------------------------------------------------------------------
// CSR build: histogram, single-block exclusive scan, ticket scatter.
// ---------------------------------------------------------------------------
__global__ __launch_bounds__(256) void hist_kernel(
    const int* __restrict__ rows, int* __restrict__ cnt, int n_edges) {
    int e = blockIdx.x * 256 + threadIdx.x;
    if (e < n_edges) atomicAdd(&cnt[rows[e]], 1);
}

// Single block of 1024 threads; n up to ~52k. off[0..n] exclusive offsets.
__global__ __launch_bounds__(1024) void exscan_kernel(
    const int* __restrict__ cnt, int n, int* __restrict__ off) {
    __shared__ int part[1024];
    int t = threadIdx.x;
    int chunk = (n + 1023) / 1024;
    int lo = t * chunk;
    int hi = lo + chunk; if (hi > n) hi = n;
    int s = 0;
    for (int i = lo; i < hi; i++) s += cnt[i];
    part[t] = s;
    __syncthreads();
    for (int d = 1; d < 1024; d <<= 1) {
        int v = (t >= d) ? part[t - d] : 0;
        __syncthreads();
        part[t] += v;
        __syncthreads();
    }
    int base = (t == 0) ? 0 : part[t - 1];
    for (int i = lo; i < hi; i++) {
        off[i] = base;
        base += cnt[i];
    }
    if (hi >= n) off[n] = base;  // all such threads hold the grand total
}

__global__ __launch_bounds__(256) void scatter_kernel(
    const int* __restrict__ rows, const int* __restrict__ cols,
    const float* __restrict__ vals, int* __restrict__ cursor,
    int* __restrict__ csr_cols, float* __restrict__ csr_vals, int n_edges) {
    int e = blockIdx.x * 256 + threadIdx.x;
    if (e >= n_edges) return;
    int r = rows[e];
    int p = atomicAdd(&cursor[r], 1);
    csr_cols[p] = cols[e];
    csr_vals[p] = vals[e];
}

// ---------------------------------------------------------------------------
// CSR aggregation: one 64-lane wave per row, lane owns 4 consecutive floats.
// agg[row,:] = sum_e vals[e] * support[cols[e],:]  (writes zeros for empty rows)
// ---------------------------------------------------------------------------
__global__ __launch_bounds__(256) void csr_agg_kernel(
    const float* __restrict__ support, const int* __restrict__ off,
    const int* __restrict__ ccols, const float* __restrict__ cvals,
    float* __restrict__ agg, int n_rows) {
    int gid = blockIdx.x * 256 + threadIdx.x;
    int row = gid >> 6;
    int lane = gid & 63;
    if (row >= n_rows) return;
    int beg = off[row], end = off[row + 1];
    float4 acc = {0.f, 0.f, 0.f, 0.f};
    for (int e = beg; e < end; e++) {
        int c = ccols[e];
        float v = cvals[e];
        const float4 s = *(const float4*)(support + (long)c * 256 + lane * 4);
        acc.x = fmaf(v, s.x, acc.x);
        acc.y = fmaf(v, s.y, acc.y);
        acc.z = fmaf(v, s.z, acc.z);
        acc.w = fmaf(v, s.w, acc.w);
    }
    *(float4*)(agg + (long)row * 256 + lane * 4) = acc;
}

// ---------------------------------------------------------------------------
// Column stats + BN apply (+ optional tanh)
// ---------------------------------------------------------------------------
__global__ __launch_bounds__(256) void bn_stats_kernel(
    const float* __restrict__ x, int n, float* __restrict__ stats) {
    int col = threadIdx.x;
    int r0 = blockIdx.x * 256;
    int r1 = r0 + 256;
    if (r1 > n) r1 = n;
    float s = 0.f, sq = 0.f;
    for (int r = r0; r < r1; r++) {
        float v = x[(long)r * 256 + col];
        s += v;
        sq += v * v;
    }
    atomicAdd(&stats[col], s);
    atomicAdd(&stats[256 + col], sq);
}

template <bool TANH>
__global__ __launch_bounds__(256) void bn_apply_kernel(
    const float* __restrict__ x, float* __restrict__ y, int n,
    const float* __restrict__ gamma, const float* __restrict__ beta,
    const float* __restrict__ stats) {
    long total = (long)n * 256;
    float inv_n = 1.f / (float)n;
    for (long idx = (long)blockIdx.x * 256 + threadIdx.x; idx < total;
         idx += (long)gridDim.x * 256) {
        int col = (int)(idx & 255);
        float mean = stats[col] * inv_n;
        float var = stats[256 + col] * inv_n - mean * mean;
        float sc = rsqrtf(var + BN_EPS) * gamma[col];
        float v = (x[idx] - mean) * sc + beta[col];
        if (TANH) v = tanhf(v);
        y[idx] = v;
    }
}

// ---------------------------------------------------------------------------
// Quaternion vec-vec multiplication
// ---------------------------------------------------------------------------
__global__ __launch_bounds__(256) void hr_kernel(
    const float* __restrict__ X, const float* __restrict__ R,
    const int* __restrict__ e1_idx, const int* __restrict__ r_idx,
    float* __restrict__ hr) {
    int idx = blockIdx.x * 256 + threadIdx.x;
    if (idx >= BATCH * 64) return;
    int b = idx >> 6, s = idx & 63;
    const float* h = X + (long)e1_idx[b] * 256;
    const float* p = R + (long)r_idx[b] * 256;
    float qr = h[s], qi = h[64 + s], qj = h[128 + s], qk = h[192 + s];
    float pr = p[s], pi = p[64 + s], pj = p[128 + s], pk = p[192 + s];
    float inv = rsqrtf(pr * pr + pi * pi + pj * pj + pk * pk);
    pr *= inv; pi *= inv; pj *= inv; pk *= inv;
    float* o = hr + (long)b * 256 + s;
    o[0]   = qr * pr - qi * pi - qj * pj - qk * pk;
    o[64]  = qi * pr + qr * pi - qk * pj + qj * pk;
    o[128] = qj * pr + qk * pi + qr * pj - qi * pk;
    o[192] = qk * pr - qj * pi + qi * pj + qr * pk;
}

// ---------------------------------------------------------------------------
// Host-side orchestration
// ---------------------------------------------------------------------------
struct Csr {
    int* off;      // n+1
    int* cur;      // n (also used as histogram buffer)
    int* ccols;    // NEDGE
    float* cvals;  // NEDGE
};

struct Ws {
    float* supportBuf;  // (50500,256)
    float* aggA;        // (50500,256)
    float* aggB;        // (50000,256)
    float* XRcur;       // (50500,256)
    float* H256;        // (256,256)
    float* H512;        // (512,256)
    float* hr;          // (512,256)
    float* hrn;         // (512,256)
    float* stats;       // 512
    Csr adj;            // n_rows = N_ENTS
    Csr adjr;           // n_rows = N_ALL
};

static void build_csr(const int* rows, const int* cols, const float* vals,
                      int n_rows, const Csr& c, hipStream_t stream) {
    hipMemsetAsync(c.cur, 0, (size_t)n_rows * sizeof(int), stream);
    hist_kernel<<<(NEDGE + 255) / 256, 256, 0, stream>>>(rows, c.cur, NEDGE);
    exscan_kernel<<<1, 1024, 0, stream>>>(c.cur, n_rows, c.off);
    hipMemcpyAsync(c.cur, c.off, (size_t)n_rows * sizeof(int),
                   hipMemcpyDeviceToDevice, stream);
    scatter_kernel<<<(NEDGE + 255) / 256, 256, 0, stream>>>(
        rows, cols, vals, c.cur, c.ccols, c.cvals, NEDGE);
}

static void run_bn(float* buf, float* outbuf, int n, const float* gamma,
                   const float* beta, bool do_tanh, const Ws& w,
                   hipStream_t stream) {
    hipMemsetAsync(w.stats, 0, 512 * sizeof(float), stream);
    bn_stats_kernel<<<(n + 255) / 256, 256, 0, stream>>>(buf, n, w.stats);
    long total = (long)n * 256;
    int blocks = (int)((total + 255) / 256);
    if (blocks > 2048) blocks = 2048;
    if (do_tanh)
        bn_apply_kernel<true><<<blocks, 256, 0, stream>>>(buf, outbuf, n, gamma, beta, w.stats);
    else
        bn_apply_kernel<false><<<blocks, 256, 0, stream>>>(buf, outbuf, n, gamma, beta, w.stats);
}

static void run_q4gnn(const float* Xin, int n, const Csr& c,
                      const float* W, const float* gamma,
                      const float* beta, float* agg, const Ws& w,
                      hipStream_t stream) {
    build_hamilton_kernel<<<(4 * 64 * 256) / 256, 256, 0, stream>>>(W, w.H256, 64);
    dim3 g(4, (n + 63) / 64);
    gemm_nn_kernel<<<g, 256, 0, stream>>>(Xin, w.H256, w.supportBuf, n, 256, 256);
    int agg_blocks = (n * 64 + 255) / 256;
    csr_agg_kernel<<<agg_blocks, 256, 0, stream>>>(
        w.supportBuf, c.off, c.ccols, c.cvals, agg, n);
    run_bn(agg, agg, n, gamma, beta, true, w, stream);
}

static void run_score(const float* X, const float* R, const int* e1_idx,
                      const int* r_idx, const float* gamma, const float* beta,
                      float* out_l, const Ws& w, hipStream_t stream) {
    hr_kernel<<<(BATCH * 64) / 256, 256, 0, stream>>>(X, R, e1_idx, r_idx, w.hr);
    run_bn(w.hr, w.hrn, BATCH, gamma, beta, false, w, stream);
    dim3 g((N_ENTS + 63) / 64, BATCH / 64);
    gemm_nt_sig_kernel<<<g, 256, 0, stream>>>(w.hrn, X, out_l);
}

extern "C" void kernel_launch(void* const* d_in, const int* in_sizes, int n_in,
                              void* d_out, int out_size, void* d_ws, size_t ws_size,
                              hipStream_t stream) {
    const int*   e1_idx     = (const int*)d_in[0];
    const int*   r_idx      = (const int*)d_in[1];
    const float* emb        = (const float*)d_in[2];
    const float* gcn1_w     = (const float*)d_in[3];
    const float* gcn2_w     = (const float*)d_in[4];
    const float* gcn1_gamma = (const float*)d_in[5];
    const float* gcn1_beta  = (const float*)d_in[6];
    const float* gcn2_gamma = (const float*)d_in[7];
    const float* gcn2_beta  = (const float*)d_in[8];
    const float* lin_ents   = (const float*)d_in[9];
    const float* bn_s_gamma = (const float*)d_in[10];
    const float* bn_s_beta  = (const float*)d_in[11];
    const int*   adj_rows   = (const int*)d_in[12];
    const int*   adj_cols   = (const int*)d_in[13];
    const float* adj_vals   = (const float*)d_in[14];
    const int*   adjr_rows  = (const int*)d_in[15];
    const int*   adjr_cols  = (const int*)d_in[16];
    const float* adjr_vals  = (const float*)d_in[17];
    float* out = (float*)d_out;

    Ws w;
    float* f = (float*)d_ws;
    w.supportBuf = f; f += (long)N_ALL * EMB;
    w.aggA       = f; f += (long)N_ALL * EMB;
    w.aggB       = f; f += (long)N_ENTS * EMB;
    w.XRcur      = f; f += (long)N_ALL * EMB;
    w.H256       = f; f += 256 * 256;
    w.H512       = f; f += 512 * 256;
    w.hr         = f; f += BATCH * EMB;
    w.hrn        = f; f += BATCH * EMB;
    w.stats      = f; f += 512;
    int* ip = (int*)f;
    w.adj.off    = ip; ip += N_ENTS + 1;
    w.adj.cur    = ip; ip += N_ENTS;
    w.adj.ccols  = ip; ip += NEDGE;
    w.adjr.off   = ip; ip += N_ALL + 1;
    w.adjr.cur   = ip; ip += N_ALL;
    w.adjr.ccols = ip; ip += NEDGE;
    w.adj.cvals  = (float*)ip; ip += NEDGE;
    w.adjr.cvals = (float*)ip; ip += NEDGE;

    // Build both CSRs once; reused by both layers.
    build_csr(adj_rows, adj_cols, adj_vals, N_ENTS, w.adj, stream);
    build_csr(adjr_rows, adjr_cols, adjr_vals, N_ALL, w.adjr, stream);

    // score 0
    run_score(emb, emb + (long)N_ENTS * EMB, e1_idx, r_idx,
              bn_s_gamma, bn_s_beta, out, w, stream);

    for (int l = 0; l < 2; l++) {
        const float* XRptr = (l == 0) ? emb : w.XRcur;
        run_q4gnn(XRptr, N_ALL, w.adjr,
                  gcn2_w + (long)l * 64 * 256, gcn2_gamma + l * 256,
                  gcn2_beta + l * 256, w.aggA, w, stream);
        run_q4gnn(XRptr, N_ENTS, w.adj,
                  gcn1_w + (long)l * 64 * 256, gcn1_gamma + l * 256,
                  gcn1_beta + l * 256, w.aggB, w, stream);
        build_hamilton_kernel<<<(4 * 128 * 256) / 256, 256, 0, stream>>>(
            lin_ents + (long)l * 128 * 256, w.H512, 128);
        dim3 g(4, (N_ENTS + 63) / 64);
        gemm_lin_kernel<<<g, 256, 0, stream>>>(w.aggB, w.aggA, w.H512, w.XRcur, N_ENTS);
        hipMemcpyAsync(w.XRcur + (long)N_ENTS * EMB, w.aggA + (long)N_ENTS * EMB,
                       (size_t)N_RELS * EMB * sizeof(float),
                       hipMemcpyDeviceToDevice, stream);
        run_score(w.XRcur, w.XRcur + (long)N_ENTS * EMB, e1_idx, r_idx,
                  bn_s_gamma + (l + 1) * 256, bn_s_beta + (l + 1) * 256,
                  out + (long)(l + 1) * BATCH * N_ENTS, w, stream);
    }
}